// Round 3
// baseline (301.065 us; speedup 1.0000x reference)
//
#include <hip/hip_runtime.h>
#include <hip/hip_bf16.h>
#include <stdint.h>

#define B_ 16
#define N_ 4096
#define E_ 65536
#define C_ 128   // CIN == COUT

using f32x4 = __attribute__((ext_vector_type(4))) float;
using s16x8 = __attribute__((ext_vector_type(8))) short;

__device__ __forceinline__ unsigned short f2bf(float f) {
  unsigned int u = __builtin_bit_cast(unsigned int, f);
  u = (u + 0x7FFFu + ((u >> 16) & 1u)) >> 16;
  return (unsigned short)u;
}

// ---- CSR build (all kernels XCD-pinned: xcd x owns batches 2x, 2x+1) -----

// grid 256: zero cnt+cur for batch b, chunk of 256 ints each
__global__ __launch_bounds__(256) void zero_kernel(int* __restrict__ cnt,
                                                   int* __restrict__ cur) {
  int xcd = blockIdx.x & 7;
  int j   = blockIdx.x >> 3;           // 0..31
  int b   = xcd * 2 + (j >> 4);
  int idx = b * N_ + ((j & 15) << 8) + threadIdx.x;
  cnt[idx] = 0;
  cur[idx] = 0;
}

// grid 4096: histogram of rows, pinned per batch
__global__ __launch_bounds__(256) void hist_kernel(const int* __restrict__ rows,
                                                   int* __restrict__ cnt) {
  int xcd = blockIdx.x & 7;
  int j   = blockIdx.x >> 3;           // 0..511
  int b   = xcd * 2 + (j >> 8);
  int e   = ((j & 255) << 8) + threadIdx.x;
  int r   = rows[b * E_ + e];
  atomicAdd(&cnt[b * N_ + r], 1);
}

// grid 16: exclusive scan per batch (block bi -> batch (bi&7)*2 + (bi>>3))
__global__ __launch_bounds__(256) void scan_kernel(const int* __restrict__ cnt,
                                                   int* __restrict__ off) {
  __shared__ int psum[256];
  int b = (blockIdx.x & 7) * 2 + (blockIdx.x >> 3);
  int t = threadIdx.x;
  int local[16];
  int s = 0;
  int base = b * N_ + t * 16;
  #pragma unroll
  for (int i = 0; i < 16; ++i) { local[i] = cnt[base + i]; s += local[i]; }
  psum[t] = s;
  __syncthreads();
  if (t == 0) {
    int run = 0;
    for (int i = 0; i < 256; ++i) { int v = psum[i]; psum[i] = run; run += v; }
  }
  __syncthreads();
  int run = psum[t];
  int ob = b * (N_ + 1) + t * 16;
  #pragma unroll
  for (int i = 0; i < 16; ++i) { off[ob + i] = run; run += local[i]; }
  if (t == 255) off[b * (N_ + 1) + N_] = run;
}

// grid 4096: scatter edges into row-sorted order carrying (col, val) payload
__global__ __launch_bounds__(256) void scatter_kernel(const int* __restrict__ rows,
                                                      const int* __restrict__ cols,
                                                      const float* __restrict__ vals,
                                                      const int* __restrict__ off,
                                                      int* __restrict__ cur,
                                                      int2* __restrict__ ecv) {
  int xcd = blockIdx.x & 7;
  int j   = blockIdx.x >> 3;
  int b   = xcd * 2 + (j >> 8);
  int e   = ((j & 255) << 8) + threadIdx.x;
  int eg  = b * E_ + e;
  int r   = rows[eg];
  int slot = off[b * (N_ + 1) + r] + atomicAdd(&cur[b * N_ + r], 1);
  ecv[b * E_ + slot] = make_int2(cols[eg], __float_as_int(vals[eg]));
}

// ---- SpMM: dst[row] = ca * sum_{e in row} val_e * src[col_e] + cb * sub[row]
// wave = 4 edge-slots x 16 channel-lanes; 2-deep edge pipeline per lane.

__global__ __launch_bounds__(256) void spmm_kernel(const float* __restrict__ src,
                                                   const float* sub,
                                                   float* dst,
                                                   const int2* __restrict__ ecv,
                                                   const int* __restrict__ off,
                                                   float ca, float cb) {
  int lane = threadIdx.x & 63;
  int wv   = threadIdx.x >> 6;
  int xcd  = blockIdx.x & 7;
  int j    = blockIdx.x >> 3;          // 0..2047
  int b    = xcd * 2 + (j >> 10);
  int n    = ((j & 1023) << 2) | wv;   // row within batch
  int eg   = lane >> 4;                // edge slot 0..3
  int cl   = lane & 15;                // channel group (8 floats)
  int start = off[b * (N_ + 1) + n];
  int end   = off[b * (N_ + 1) + n + 1];
  const int2*  ecvb = ecv + b * E_;
  const float* srcb = src + (size_t)b * N_ * C_;
  float acc[8];
  #pragma unroll
  for (int t = 0; t < 8; ++t) acc[t] = 0.f;
  int s = start + eg;
  // 2-deep: consume edges s and s+4 per iteration; both gathers in flight
  for (; s + 4 < end; s += 8) {
    int2 ca2 = ecvb[s];
    int2 cb2 = ecvb[s + 4];
    float va = __builtin_bit_cast(float, ca2.y);
    float vb = __builtin_bit_cast(float, cb2.y);
    const float4* pa = reinterpret_cast<const float4*>(srcb + (size_t)ca2.x * C_ + cl * 8);
    const float4* pb = reinterpret_cast<const float4*>(srcb + (size_t)cb2.x * C_ + cl * 8);
    float4 a0 = pa[0];
    float4 a1 = pa[1];
    float4 b0 = pb[0];
    float4 b1 = pb[1];
    acc[0] = fmaf(va, a0.x, acc[0]);
    acc[1] = fmaf(va, a0.y, acc[1]);
    acc[2] = fmaf(va, a0.z, acc[2]);
    acc[3] = fmaf(va, a0.w, acc[3]);
    acc[4] = fmaf(va, a1.x, acc[4]);
    acc[5] = fmaf(va, a1.y, acc[5]);
    acc[6] = fmaf(va, a1.z, acc[6]);
    acc[7] = fmaf(va, a1.w, acc[7]);
    acc[0] = fmaf(vb, b0.x, acc[0]);
    acc[1] = fmaf(vb, b0.y, acc[1]);
    acc[2] = fmaf(vb, b0.z, acc[2]);
    acc[3] = fmaf(vb, b0.w, acc[3]);
    acc[4] = fmaf(vb, b1.x, acc[4]);
    acc[5] = fmaf(vb, b1.y, acc[5]);
    acc[6] = fmaf(vb, b1.z, acc[6]);
    acc[7] = fmaf(vb, b1.w, acc[7]);
  }
  if (s < end) {
    int2 cv = ecvb[s];
    float v = __builtin_bit_cast(float, cv.y);
    const float4* xp = reinterpret_cast<const float4*>(srcb + (size_t)cv.x * C_ + cl * 8);
    float4 x0 = xp[0];
    float4 x1 = xp[1];
    acc[0] = fmaf(v, x0.x, acc[0]);
    acc[1] = fmaf(v, x0.y, acc[1]);
    acc[2] = fmaf(v, x0.z, acc[2]);
    acc[3] = fmaf(v, x0.w, acc[3]);
    acc[4] = fmaf(v, x1.x, acc[4]);
    acc[5] = fmaf(v, x1.y, acc[5]);
    acc[6] = fmaf(v, x1.z, acc[6]);
    acc[7] = fmaf(v, x1.w, acc[7]);
  }
  // reduce the 4 edge-slots
  #pragma unroll
  for (int t = 0; t < 8; ++t) {
    acc[t] += __shfl_xor(acc[t], 16);
    acc[t] += __shfl_xor(acc[t], 32);
  }
  if (eg == 0) {
    size_t ro = ((size_t)(b * N_ + n)) * C_ + cl * 8;
    float o[8];
    #pragma unroll
    for (int t = 0; t < 8; ++t) o[t] = ca * acc[t];
    if (sub) {
      const float4* sp = reinterpret_cast<const float4*>(sub + ro);
      float4 s0 = sp[0];
      float4 s1 = sp[1];
      o[0] = fmaf(cb, s0.x, o[0]);
      o[1] = fmaf(cb, s0.y, o[1]);
      o[2] = fmaf(cb, s0.z, o[2]);
      o[3] = fmaf(cb, s0.w, o[3]);
      o[4] = fmaf(cb, s1.x, o[4]);
      o[5] = fmaf(cb, s1.y, o[5]);
      o[6] = fmaf(cb, s1.z, o[6]);
      o[7] = fmaf(cb, s1.w, o[7]);
    }
    float4* dp = reinterpret_cast<float4*>(dst + ro);
    dp[0] = make_float4(o[0], o[1], o[2], o[3]);
    dp[1] = make_float4(o[4], o[5], o[6], o[7]);
  }
}

// ---- W fragment packing: bf16, per-lane MFMA B-operand order -------------

__global__ __launch_bounds__(256) void wfrag_kernel(const float* __restrict__ w,
                                                    unsigned short* __restrict__ wf) {
  int tid = blockIdx.x * 256 + threadIdx.x;   // 0..65535
  int j  = tid & 7;
  int l  = (tid >> 3) & 63;
  int ct = (tid >> 9) & 7;
  int ks = tid >> 12;
  int g  = l >> 4;
  int k  = ks * 32 + g * 8 + j;
  int kk = k >> 7;
  int i  = k & 127;
  int o  = ct * 16 + (l & 15);
  wf[tid] = f2bf(w[(kk * C_ + i) * C_ + o]);
}

// ---- fused GEMM: out = relu(bias + x@W0 + c1@W1 + c2@W2 + c3@W3) ---------
// block = 256 (4 waves); each wave: 16 rows x 128 cols, K = 512 in 16 steps.
// NOTE: c3 may alias out (wave reads exactly the rows it later writes).

__global__ __launch_bounds__(256) void gemm_kernel(const float* __restrict__ x,
                                                   const float* __restrict__ c1,
                                                   const float* __restrict__ c2,
                                                   const float* c3,
                                                   const unsigned short* __restrict__ wf,
                                                   const float* __restrict__ bias,
                                                   float* out) {
  int lane = threadIdx.x & 63;
  int w = threadIdx.x >> 6;
  int xcd = blockIdx.x & 7;
  int j = blockIdx.x >> 3;                 // 0..127
  int b = xcd * 2 + (j >> 6);
  int mb = b * N_ + ((j & 63) << 6) + w * 16;
  int g  = lane >> 4;
  int rl = lane & 15;
  const float* srcs[4] = {x, c1, c2, c3};
  f32x4 acc[8];
  #pragma unroll
  for (int t = 0; t < 8; ++t) acc[t] = (f32x4){0.f, 0.f, 0.f, 0.f};
  size_t mrow = (size_t)(mb + rl) * C_;
  for (int ks = 0; ks < 16; ++ks) {
    const float* ap = srcs[ks >> 2] + mrow + (ks & 3) * 32 + g * 8;
    float4 a0 = *reinterpret_cast<const float4*>(ap);
    float4 a1 = *reinterpret_cast<const float4*>(ap + 4);
    s16x8 af;
    af[0] = (short)f2bf(a0.x); af[1] = (short)f2bf(a0.y);
    af[2] = (short)f2bf(a0.z); af[3] = (short)f2bf(a0.w);
    af[4] = (short)f2bf(a1.x); af[5] = (short)f2bf(a1.y);
    af[6] = (short)f2bf(a1.z); af[7] = (short)f2bf(a1.w);
    const s16x8* wp = reinterpret_cast<const s16x8*>(wf) + (ks * 8) * 64 + lane;
    #pragma unroll
    for (int ct = 0; ct < 8; ++ct) {
      s16x8 bfv = wp[ct * 64];
      acc[ct] = __builtin_amdgcn_mfma_f32_16x16x32_bf16(af, bfv, acc[ct], 0, 0, 0);
    }
  }
  #pragma unroll
  for (int ct = 0; ct < 8; ++ct) {
    int o = ct * 16 + rl;
    float bo = bias[o];
    #pragma unroll
    for (int r = 0; r < 4; ++r) {
      int m = mb + g * 4 + r;
      float val = acc[ct][r] + bo;
      out[(size_t)m * C_ + o] = val > 0.f ? val : 0.f;
    }
  }
}

// ---- launch --------------------------------------------------------------

extern "C" void kernel_launch(void* const* d_in, const int* in_sizes, int n_in,
                              void* d_out, int out_size, void* d_ws, size_t ws_size,
                              hipStream_t stream) {
  (void)in_sizes; (void)n_in; (void)out_size; (void)ws_size;
  const float* x    = (const float*)d_in[0];
  const float* vals = (const float*)d_in[1];
  const float* wts  = (const float*)d_in[2];
  const float* bias = (const float*)d_in[3];
  const int*   rows = (const int*)d_in[4];
  const int*   cols = (const int*)d_in[5];
  float* out = (float*)d_out;

  const size_t S = (size_t)B_ * N_ * C_ * sizeof(float);   // 33.5 MB
  char* ws = (char*)d_ws;
  float* cheb1 = (float*)ws;
  float* cheb2 = (float*)(ws + S);
  char* meta = ws + 2 * S;
  int* cnt  = (int*)meta;                        // B*N*4      = 262144 B
  int* cur  = (int*)(meta + 262144);             // B*N*4      = 262144 B
  int* off  = (int*)(meta + 524288);             // B*(N+1)*4  = 262208 B
  int2* ecv = (int2*)(meta + 1048576);           // B*E*8      = 8 MB
  unsigned short* wf = (unsigned short*)(meta + 1048576 + 8388608);  // 128 KB

  zero_kernel<<<256, 256, 0, stream>>>(cnt, cur);
  wfrag_kernel<<<256, 256, 0, stream>>>(wts, wf);
  hist_kernel<<<(B_ * E_) / 256, 256, 0, stream>>>(rows, cnt);
  scan_kernel<<<B_, 256, 0, stream>>>(cnt, off);
  scatter_kernel<<<(B_ * E_) / 256, 256, 0, stream>>>(rows, cols, vals, off, cur, ecv);
  // cheb1 = L x
  spmm_kernel<<<(B_ * N_) / 4, 256, 0, stream>>>(x, nullptr, cheb1, ecv, off, 1.f, 0.f);
  // cheb2 = 2 L cheb1 - x
  spmm_kernel<<<(B_ * N_) / 4, 256, 0, stream>>>(cheb1, x, cheb2, ecv, off, 2.f, -1.f);
  // cheb3 = 2 L cheb2 - cheb1   (stored in d_out)
  spmm_kernel<<<(B_ * N_) / 4, 256, 0, stream>>>(cheb2, cheb1, out, ecv, off, 2.f, -1.f);
  // out = relu(bias + x@W0 + c1@W1 + c2@W2 + c3@W3)
  gemm_kernel<<<(B_ * N_) / 64, 256, 0, stream>>>(x, cheb1, cheb2, out, wf, bias, out);
}

// Round 4
// 147.536 us; speedup vs baseline: 2.0406x; 2.0406x over previous
//
#include <hip/hip_runtime.h>
#include <hip/hip_bf16.h>
#include <stdint.h>

#define B_ 16
#define N_ 4096
#define E_ 65536
#define C_ 128   // CIN == COUT

typedef unsigned short u16;
typedef unsigned int u32;
using f32x4 = __attribute__((ext_vector_type(4))) float;
using s16x8 = __attribute__((ext_vector_type(8))) short;

__device__ __forceinline__ u16 f2bf(float f) {
  u32 u = __builtin_bit_cast(u32, f);
  u = (u + 0x7FFFu + ((u >> 16) & 1u)) >> 16;
  return (u16)u;
}
__device__ __forceinline__ float bflo(u32 u) {   // low bf16 -> f32
  return __builtin_bit_cast(float, u << 16);
}
__device__ __forceinline__ float bfhi(u32 u) {   // high bf16 -> f32
  return __builtin_bit_cast(float, u & 0xFFFF0000u);
}

// ---- x -> bf16 conversion (XCD-pinned: xcd x owns batches 2x,2x+1) -------

__global__ __launch_bounds__(256) void xconv_kernel(const float* __restrict__ x,
                                                    u16* __restrict__ xb) {
  int xcd = blockIdx.x & 7;
  int j   = blockIdx.x >> 3;              // 0..511
  int b   = xcd * 2 + (j >> 8);
  size_t base = (size_t)b * N_ * C_ + ((j & 255) * 256 + threadIdx.x) * 8;
  const float4* xp = reinterpret_cast<const float4*>(x + base);
  float4 a0 = xp[0];
  float4 a1 = xp[1];
  uint4 p;
  p.x = (u32)f2bf(a0.x) | ((u32)f2bf(a0.y) << 16);
  p.y = (u32)f2bf(a0.z) | ((u32)f2bf(a0.w) << 16);
  p.z = (u32)f2bf(a1.x) | ((u32)f2bf(a1.y) << 16);
  p.w = (u32)f2bf(a1.z) | ((u32)f2bf(a1.w) << 16);
  *reinterpret_cast<uint4*>(xb + base) = p;
}

// ---- CSR build, atomic-free (LDS histograms + LDS ranking) ---------------
// hist layout: [b][c][r], b in 16, c in 16 chunks of 4096 edges, r in 4096.

__global__ __launch_bounds__(256) void hist_kernel(const int* __restrict__ rows,
                                                   int* __restrict__ hist) {
  __shared__ int h[N_];
  int b = blockIdx.x >> 4;
  int c = blockIdx.x & 15;
  int t = threadIdx.x;
  #pragma unroll
  for (int i = 0; i < 16; ++i) h[t + 256 * i] = 0;
  __syncthreads();
  int ebase = b * E_ + c * 4096;
  #pragma unroll
  for (int i = 0; i < 16; ++i) {
    int r = rows[ebase + t + 256 * i];
    atomicAdd(&h[r], 1);                 // LDS atomic
  }
  __syncthreads();
  int4* hg = reinterpret_cast<int4*>(hist + (size_t)blockIdx.x * 4096);
  const int4* hl = reinterpret_cast<const int4*>(h);
  #pragma unroll
  for (int i = 0; i < 4; ++i) hg[t + 256 * i] = hl[t + 256 * i];
}

// per-row exclusive scan over the 16 chunk counts (in-place), emit row totals
__global__ __launch_bounds__(256) void rowscan_kernel(int* __restrict__ hist,
                                                      int* __restrict__ cnt) {
  int rg = blockIdx.x * 256 + threadIdx.x;   // 0..65535 = b*4096+r
  int b = rg >> 12;
  int r = rg & 4095;
  int base = (b * 16) * 4096 + r;
  int h[16];
  #pragma unroll
  for (int c = 0; c < 16; ++c) h[c] = hist[base + c * 4096];
  int run = 0;
  #pragma unroll
  for (int c = 0; c < 16; ++c) {
    int v = h[c];
    hist[base + c * 4096] = run;
    run += v;
  }
  cnt[rg] = run;
}

// per-batch exclusive scan of row totals -> off
__global__ __launch_bounds__(256) void scan_kernel(const int* __restrict__ cnt,
                                                   int* __restrict__ off) {
  __shared__ int psum[256];
  int b = (blockIdx.x & 7) * 2 + (blockIdx.x >> 3);
  int t = threadIdx.x;
  int local[16];
  int s = 0;
  int base = b * N_ + t * 16;
  #pragma unroll
  for (int i = 0; i < 16; ++i) { local[i] = cnt[base + i]; s += local[i]; }
  psum[t] = s;
  __syncthreads();
  if (t == 0) {
    int run = 0;
    for (int i = 0; i < 256; ++i) { int v = psum[i]; psum[i] = run; run += v; }
  }
  __syncthreads();
  int run = psum[t];
  int ob = b * (N_ + 1) + t * 16;
  #pragma unroll
  for (int i = 0; i < 16; ++i) { off[ob + i] = run; run += local[i]; }
  if (t == 255) off[b * (N_ + 1) + N_] = run;
}

// scatter edges row-sorted; rank via LDS atomics; payload col|bf16(val)
__global__ __launch_bounds__(256) void scatter2_kernel(const int* __restrict__ rows,
                                                       const int* __restrict__ cols,
                                                       const float* __restrict__ vals,
                                                       const int* __restrict__ off,
                                                       const int* __restrict__ hist,
                                                       u32* __restrict__ ecv) {
  __shared__ int base[N_];
  __shared__ int cur[N_];
  int xcd = blockIdx.x & 7;
  int j   = blockIdx.x >> 3;              // 0..31
  int b   = xcd * 2 + (j >> 4);
  int c   = j & 15;
  int t   = threadIdx.x;
  const int* hb = hist + (b * 16 + c) * 4096;
  const int* ob = off + b * (N_ + 1);
  #pragma unroll
  for (int i = 0; i < 16; ++i) {
    int idx = t + 256 * i;
    base[idx] = ob[idx] + hb[idx];
    cur[idx] = 0;
  }
  __syncthreads();
  int ebase = b * E_ + c * 4096;
  u32* ecvb = ecv + b * E_;
  #pragma unroll
  for (int i = 0; i < 16; ++i) {
    int e = ebase + t + 256 * i;
    int r = rows[e];
    int rank = atomicAdd(&cur[r], 1);     // LDS atomic
    u32 pv = (u32)cols[e] | ((u32)f2bf(vals[e]) << 16);
    ecvb[base[r] + rank] = pv;
  }
}

// ---- SpMM (bf16): dst[row] = ca * sum val_e * src[col_e] + cb * sub[row]
// wave = 4 edge-slots x 16 channel-lanes; clamped 4-deep unroll.

__global__ __launch_bounds__(256) void spmm_kernel(const u16* __restrict__ src,
                                                   const u16* sub,
                                                   u16* __restrict__ dst,
                                                   const u32* __restrict__ ecv,
                                                   const int* __restrict__ off,
                                                   float ca, float cb) {
  int lane = threadIdx.x & 63;
  int wv   = threadIdx.x >> 6;
  int xcd  = blockIdx.x & 7;
  int j    = blockIdx.x >> 3;          // 0..2047
  int b    = xcd * 2 + (j >> 10);
  int n    = ((j & 1023) << 2) | wv;   // row within batch
  int eg   = lane >> 4;                // edge slot 0..3
  int cl   = lane & 15;                // channel group (8 bf16 = 16B)
  int start = off[b * (N_ + 1) + n];
  int end   = off[b * (N_ + 1) + n + 1];
  const u32* ecvb = ecv + b * E_;
  const u16* srcb = src + (size_t)b * N_ * C_;
  float acc[8];
  #pragma unroll
  for (int t = 0; t < 8; ++t) acc[t] = 0.f;
  for (int s0 = start; s0 < end; s0 += 16) {
    #pragma unroll
    for (int d = 0; d < 4; ++d) {
      int idx = s0 + eg + d * 4;
      bool in = idx < end;
      u32 cv = ecvb[in ? idx : start];
      float v = in ? bfhi(cv) : 0.f;
      int col = cv & 0xFFFFu;
      uint4 u = *reinterpret_cast<const uint4*>(srcb + col * C_ + cl * 8);
      acc[0] = fmaf(v, bflo(u.x), acc[0]);
      acc[1] = fmaf(v, bfhi(u.x), acc[1]);
      acc[2] = fmaf(v, bflo(u.y), acc[2]);
      acc[3] = fmaf(v, bfhi(u.y), acc[3]);
      acc[4] = fmaf(v, bflo(u.z), acc[4]);
      acc[5] = fmaf(v, bfhi(u.z), acc[5]);
      acc[6] = fmaf(v, bflo(u.w), acc[6]);
      acc[7] = fmaf(v, bfhi(u.w), acc[7]);
    }
  }
  #pragma unroll
  for (int t = 0; t < 8; ++t) {
    acc[t] += __shfl_xor(acc[t], 16);
    acc[t] += __shfl_xor(acc[t], 32);
  }
  if (eg == 0) {
    size_t ro = ((size_t)(b * N_ + n)) * C_ + cl * 8;
    float o[8];
    #pragma unroll
    for (int t = 0; t < 8; ++t) o[t] = ca * acc[t];
    if (sub) {
      uint4 su = *reinterpret_cast<const uint4*>(sub + ro);
      o[0] = fmaf(cb, bflo(su.x), o[0]);
      o[1] = fmaf(cb, bfhi(su.x), o[1]);
      o[2] = fmaf(cb, bflo(su.y), o[2]);
      o[3] = fmaf(cb, bfhi(su.y), o[3]);
      o[4] = fmaf(cb, bflo(su.z), o[4]);
      o[5] = fmaf(cb, bfhi(su.z), o[5]);
      o[6] = fmaf(cb, bflo(su.w), o[6]);
      o[7] = fmaf(cb, bfhi(su.w), o[7]);
    }
    uint4 p;
    p.x = (u32)f2bf(o[0]) | ((u32)f2bf(o[1]) << 16);
    p.y = (u32)f2bf(o[2]) | ((u32)f2bf(o[3]) << 16);
    p.z = (u32)f2bf(o[4]) | ((u32)f2bf(o[5]) << 16);
    p.w = (u32)f2bf(o[6]) | ((u32)f2bf(o[7]) << 16);
    *reinterpret_cast<uint4*>(dst + ro) = p;
  }
}

// ---- W fragment packing: bf16, per-lane MFMA B-operand order -------------

__global__ __launch_bounds__(256) void wfrag_kernel(const float* __restrict__ w,
                                                    u16* __restrict__ wf) {
  int tid = blockIdx.x * 256 + threadIdx.x;   // 0..65535
  int j  = tid & 7;
  int l  = (tid >> 3) & 63;
  int ct = (tid >> 9) & 7;
  int ks = tid >> 12;
  int g  = l >> 4;
  int k  = ks * 32 + g * 8 + j;
  int kk = k >> 7;
  int i  = k & 127;
  int o  = ct * 16 + (l & 15);
  wf[tid] = f2bf(w[(kk * C_ + i) * C_ + o]);
}

// ---- fused GEMM: out = relu(bias + x@W0 + c1@W1 + c2@W2 + c3@W3) ---------
// block = 256 (4 waves); each wave: 16 rows x 128 cols, K = 512 in 16 steps.

__global__ __launch_bounds__(256) void gemm_kernel(const u16* __restrict__ x,
                                                   const u16* __restrict__ c1,
                                                   const u16* __restrict__ c2,
                                                   const u16* __restrict__ c3,
                                                   const u16* __restrict__ wf,
                                                   const float* __restrict__ bias,
                                                   float* __restrict__ out) {
  int lane = threadIdx.x & 63;
  int w = threadIdx.x >> 6;
  int xcd = blockIdx.x & 7;
  int j = blockIdx.x >> 3;                 // 0..127
  int b = xcd * 2 + (j >> 6);
  int mb = b * N_ + ((j & 63) << 6) + w * 16;
  int g  = lane >> 4;
  int rl = lane & 15;
  const u16* srcs[4] = {x, c1, c2, c3};
  f32x4 acc[8];
  #pragma unroll
  for (int t = 0; t < 8; ++t) acc[t] = (f32x4){0.f, 0.f, 0.f, 0.f};
  size_t mrow = (size_t)(mb + rl) * C_;
  for (int ks = 0; ks < 16; ++ks) {
    const u16* ap = srcs[ks >> 2] + mrow + (ks & 3) * 32 + g * 8;
    s16x8 af = *reinterpret_cast<const s16x8*>(ap);
    const s16x8* wp = reinterpret_cast<const s16x8*>(wf) + (ks * 8) * 64 + lane;
    #pragma unroll
    for (int ct = 0; ct < 8; ++ct) {
      s16x8 bfv = wp[ct * 64];
      acc[ct] = __builtin_amdgcn_mfma_f32_16x16x32_bf16(af, bfv, acc[ct], 0, 0, 0);
    }
  }
  #pragma unroll
  for (int ct = 0; ct < 8; ++ct) {
    int o = ct * 16 + rl;
    float bo = bias[o];
    #pragma unroll
    for (int r = 0; r < 4; ++r) {
      int m = mb + g * 4 + r;
      float val = acc[ct][r] + bo;
      out[(size_t)m * C_ + o] = val > 0.f ? val : 0.f;
    }
  }
}

// ---- launch --------------------------------------------------------------

extern "C" void kernel_launch(void* const* d_in, const int* in_sizes, int n_in,
                              void* d_out, int out_size, void* d_ws, size_t ws_size,
                              hipStream_t stream) {
  (void)in_sizes; (void)n_in; (void)out_size; (void)ws_size;
  const float* x    = (const float*)d_in[0];
  const float* vals = (const float*)d_in[1];
  const float* wts  = (const float*)d_in[2];
  const float* bias = (const float*)d_in[3];
  const int*   rows = (const int*)d_in[4];
  const int*   cols = (const int*)d_in[5];
  float* out = (float*)d_out;

  const size_t SB = (size_t)B_ * N_ * C_ * sizeof(u16);   // 16.78 MB
  char* ws = (char*)d_ws;
  u16* xb  = (u16*)ws;
  u16* c1b = (u16*)(ws + SB);
  u16* c2b = (u16*)(ws + 2 * SB);
  u16* c3b = (u16*)(ws + 3 * SB);
  char* meta = ws + 4 * SB;
  int* hist = (int*)meta;                         // 16*16*4096*4 = 4 MB
  u32* ecv  = (u32*)(meta + 4194304);             // B*E*4       = 4 MB
  int* cnt  = (int*)(meta + 8388608);             // B*N*4       = 256 KB
  int* off  = (int*)(meta + 8650752);             // B*(N+1)*4   = 262208 B
  u16* wf   = (u16*)(meta + 8912960);             // 128 KB

  xconv_kernel<<<4096, 256, 0, stream>>>(x, xb);
  wfrag_kernel<<<256, 256, 0, stream>>>(wts, wf);
  hist_kernel<<<256, 256, 0, stream>>>(rows, hist);
  rowscan_kernel<<<256, 256, 0, stream>>>(hist, cnt);
  scan_kernel<<<16, 256, 0, stream>>>(cnt, off);
  scatter2_kernel<<<256, 256, 0, stream>>>(rows, cols, vals, off, hist, ecv);
  // cheb1 = L x
  spmm_kernel<<<(B_ * N_) / 4, 256, 0, stream>>>(xb, nullptr, c1b, ecv, off, 1.f, 0.f);
  // cheb2 = 2 L cheb1 - x
  spmm_kernel<<<(B_ * N_) / 4, 256, 0, stream>>>(c1b, xb, c2b, ecv, off, 2.f, -1.f);
  // cheb3 = 2 L cheb2 - cheb1
  spmm_kernel<<<(B_ * N_) / 4, 256, 0, stream>>>(c2b, c1b, c3b, ecv, off, 2.f, -1.f);
  // out = relu(bias + x@W0 + c1@W1 + c2@W2 + c3@W3)
  gemm_kernel<<<(B_ * N_) / 64, 256, 0, stream>>>(xb, c1b, c2b, c3b, wf, bias, out);
}

// Round 5
// 144.606 us; speedup vs baseline: 2.0820x; 1.0203x over previous
//
#include <hip/hip_runtime.h>
#include <hip/hip_bf16.h>
#include <stdint.h>

#define B_ 16
#define N_ 4096
#define E_ 65536
#define C_ 128   // CIN == COUT
#define ECAP 81920  // padded edge capacity per batch (E + 3*N = 77824 max)

typedef unsigned short u16;
typedef unsigned int u32;
using f32x4 = __attribute__((ext_vector_type(4))) float;
using s16x8 = __attribute__((ext_vector_type(8))) short;

__device__ __forceinline__ u16 f2bf(float f) {
  u32 u = __builtin_bit_cast(u32, f);
  u = (u + 0x7FFFu + ((u >> 16) & 1u)) >> 16;
  return (u16)u;
}
__device__ __forceinline__ float bflo(u32 u) {   // low bf16 -> f32
  return __builtin_bit_cast(float, u << 16);
}
__device__ __forceinline__ float bfhi(u32 u) {   // high bf16 -> f32
  return __builtin_bit_cast(float, u & 0xFFFF0000u);
}

// ---- prep: fused xconv (blocks 0..4095) + wfrag (4096..4351) + hist (4352..4607)
// wfrag bakes the Chebyshev recombination:
//   out = x(W0-W2) + g1(W1-3W3) + g2(2W2) + g3(4W3),  g_k = L^k x

__global__ __launch_bounds__(256) void prep_kernel(const float* __restrict__ x,
                                                   u16* __restrict__ xb,
                                                   const float* __restrict__ w,
                                                   u16* __restrict__ wf,
                                                   const int* __restrict__ rows,
                                                   int* __restrict__ hist) {
  int blk = blockIdx.x;
  int t = threadIdx.x;
  if (blk < 4096) {
    // x -> bf16, XCD-pinned
    int xcd = blk & 7;
    int j   = blk >> 3;              // 0..511
    int b   = xcd * 2 + (j >> 8);
    size_t base = (size_t)b * N_ * C_ + ((j & 255) * 256 + t) * 8;
    const float4* xp = reinterpret_cast<const float4*>(x + base);
    float4 a0 = xp[0];
    float4 a1 = xp[1];
    uint4 p;
    p.x = (u32)f2bf(a0.x) | ((u32)f2bf(a0.y) << 16);
    p.y = (u32)f2bf(a0.z) | ((u32)f2bf(a0.w) << 16);
    p.z = (u32)f2bf(a1.x) | ((u32)f2bf(a1.y) << 16);
    p.w = (u32)f2bf(a1.z) | ((u32)f2bf(a1.w) << 16);
    *reinterpret_cast<uint4*>(xb + base) = p;
  } else if (blk < 4352) {
    // W fragment pack with recombined weights, MFMA B-operand order
    int tid = (blk - 4096) * 256 + t;   // 0..65535
    int j  = tid & 7;
    int l  = (tid >> 3) & 63;
    int ct = (tid >> 9) & 7;
    int ks = tid >> 12;
    int g  = l >> 4;
    int k  = ks * 32 + g * 8 + j;       // 0..511
    int kk = k >> 7;
    int i  = k & 127;
    int o  = ct * 16 + (l & 15);
    float a = w[(kk * C_ + i) * C_ + o];
    float r;
    if (kk == 0)      r = a - w[(2 * C_ + i) * C_ + o];
    else if (kk == 1) r = a - 3.f * w[(3 * C_ + i) * C_ + o];
    else if (kk == 2) r = 2.f * a;
    else              r = 4.f * a;
    wf[tid] = f2bf(r);
  } else {
    // per-(batch,chunk) LDS histogram of rows
    __shared__ int h[N_];
    int hblk = blk - 4352;              // 0..255
    int b = hblk >> 4;
    int c = hblk & 15;
    #pragma unroll
    for (int i = 0; i < 16; ++i) h[t + 256 * i] = 0;
    __syncthreads();
    int ebase = b * E_ + c * 4096;
    #pragma unroll
    for (int i = 0; i < 16; ++i) {
      int r = rows[ebase + t + 256 * i];
      atomicAdd(&h[r], 1);              // LDS atomic
    }
    __syncthreads();
    int4* hg = reinterpret_cast<int4*>(hist + (size_t)hblk * 4096);
    const int4* hl = reinterpret_cast<const int4*>(h);
    #pragma unroll
    for (int i = 0; i < 4; ++i) hg[t + 256 * i] = hl[t + 256 * i];
  }
}

// per-row exclusive scan over the 16 chunk counts (in-place), emit row totals
__global__ __launch_bounds__(256) void rowscan_kernel(int* __restrict__ hist,
                                                      int* __restrict__ cnt) {
  int rg = blockIdx.x * 256 + threadIdx.x;   // 0..65535 = b*4096+r
  int b = rg >> 12;
  int r = rg & 4095;
  int base = (b * 16) * 4096 + r;
  int h[16];
  #pragma unroll
  for (int c = 0; c < 16; ++c) h[c] = hist[base + c * 4096];
  int run = 0;
  #pragma unroll
  for (int c = 0; c < 16; ++c) {
    int v = h[c];
    hist[base + c * 4096] = run;
    run += v;
  }
  cnt[rg] = run;
}

// per-batch exclusive scan of PADDED row totals -> off (4-aligned row starts)
__global__ __launch_bounds__(256) void scan_kernel(const int* __restrict__ cnt,
                                                   int* __restrict__ off) {
  __shared__ int psum[256];
  int b = (blockIdx.x & 7) * 2 + (blockIdx.x >> 3);
  int t = threadIdx.x;
  int local[16];
  int s = 0;
  int base = b * N_ + t * 16;
  #pragma unroll
  for (int i = 0; i < 16; ++i) {
    local[i] = (cnt[base + i] + 3) & ~3;   // pad each row to multiple of 4
    s += local[i];
  }
  psum[t] = s;
  __syncthreads();
  if (t == 0) {
    int run = 0;
    for (int i = 0; i < 256; ++i) { int v = psum[i]; psum[i] = run; run += v; }
  }
  __syncthreads();
  int run = psum[t];
  int ob = b * (N_ + 1) + t * 16;
  #pragma unroll
  for (int i = 0; i < 16; ++i) { off[ob + i] = run; run += local[i]; }
  if (t == 255) off[b * (N_ + 1) + N_] = run;
}

// scatter edges row-sorted; rank via LDS atomics; payload col|bf16(val);
// chunk-0 blocks also zero-fill the pad slots of every row.
__global__ __launch_bounds__(256) void scatter2_kernel(const int* __restrict__ rows,
                                                       const int* __restrict__ cols,
                                                       const float* __restrict__ vals,
                                                       const int* __restrict__ off,
                                                       const int* __restrict__ hist,
                                                       const int* __restrict__ cnt,
                                                       u32* __restrict__ ecv) {
  __shared__ int base[N_];
  __shared__ int cur[N_];
  int xcd = blockIdx.x & 7;
  int j   = blockIdx.x >> 3;              // 0..31
  int b   = xcd * 2 + (j >> 4);
  int c   = j & 15;
  int t   = threadIdx.x;
  const int* hb = hist + (b * 16 + c) * 4096;
  const int* ob = off + b * (N_ + 1);
  #pragma unroll
  for (int i = 0; i < 16; ++i) {
    int idx = t + 256 * i;
    base[idx] = ob[idx] + hb[idx];
    cur[idx] = 0;
  }
  __syncthreads();
  int ebase = b * E_ + c * 4096;
  u32* ecvb = ecv + (size_t)b * ECAP;
  #pragma unroll
  for (int i = 0; i < 16; ++i) {
    int e = ebase + t + 256 * i;
    int r = rows[e];
    int rank = atomicAdd(&cur[r], 1);     // LDS atomic
    u32 pv = (u32)cols[e] | ((u32)f2bf(vals[e]) << 16);
    ecvb[base[r] + rank] = pv;
  }
  if (c == 0) {
    // zero the pad tail of each row (disjoint from all real-edge slots)
    #pragma unroll
    for (int i = 0; i < 16; ++i) {
      int r = t + 256 * i;
      int real = cnt[b * N_ + r];
      int pbase = ob[r] + real;
      int pad = (-real) & 3;
      for (int k = 0; k < pad; ++k) ecvb[pbase + k] = 0;
    }
  }
}

// ---- SpMM (bf16, pure L): dst[row] = sum val_e * src[col_e]
// wave = 4 group-slots x 16 channel-lanes; each slot loads uint4 = 4 edges.

__global__ __launch_bounds__(256) void spmm_kernel(const u16* __restrict__ src,
                                                   u16* __restrict__ dst,
                                                   const u32* __restrict__ ecv,
                                                   const int* __restrict__ off) {
  int lane = threadIdx.x & 63;
  int wv   = threadIdx.x >> 6;
  int xcd  = blockIdx.x & 7;
  int j    = blockIdx.x >> 3;          // 0..2047
  int b    = xcd * 2 + (j >> 10);
  int n    = ((j & 1023) << 2) | wv;   // row within batch
  int eg   = lane >> 4;                // group slot 0..3
  int cl   = lane & 15;                // channel group (8 bf16 = 16B)
  int s4 = off[b * (N_ + 1) + n] >> 2;
  int e4 = off[b * (N_ + 1) + n + 1] >> 2;
  const uint4* ecv4 = reinterpret_cast<const uint4*>(ecv + (size_t)b * ECAP);
  const u16* srcb = src + (size_t)b * N_ * C_;
  float acc[8];
  #pragma unroll
  for (int t = 0; t < 8; ++t) acc[t] = 0.f;
  for (int gp = s4 + eg; gp < e4; gp += 4) {
    uint4 cv = ecv4[gp];
    u32 e0 = cv.x, e1 = cv.y, e2 = cv.z, e3 = cv.w;
    uint4 u0 = *reinterpret_cast<const uint4*>(srcb + (size_t)(e0 & 0xFFFFu) * C_ + cl * 8);
    uint4 u1 = *reinterpret_cast<const uint4*>(srcb + (size_t)(e1 & 0xFFFFu) * C_ + cl * 8);
    uint4 u2 = *reinterpret_cast<const uint4*>(srcb + (size_t)(e2 & 0xFFFFu) * C_ + cl * 8);
    uint4 u3 = *reinterpret_cast<const uint4*>(srcb + (size_t)(e3 & 0xFFFFu) * C_ + cl * 8);
    float v0 = bfhi(e0), v1 = bfhi(e1), v2 = bfhi(e2), v3 = bfhi(e3);
    acc[0] = fmaf(v0, bflo(u0.x), acc[0]);
    acc[1] = fmaf(v0, bfhi(u0.x), acc[1]);
    acc[2] = fmaf(v0, bflo(u0.y), acc[2]);
    acc[3] = fmaf(v0, bfhi(u0.y), acc[3]);
    acc[4] = fmaf(v0, bflo(u0.z), acc[4]);
    acc[5] = fmaf(v0, bfhi(u0.z), acc[5]);
    acc[6] = fmaf(v0, bflo(u0.w), acc[6]);
    acc[7] = fmaf(v0, bfhi(u0.w), acc[7]);
    acc[0] = fmaf(v1, bflo(u1.x), acc[0]);
    acc[1] = fmaf(v1, bfhi(u1.x), acc[1]);
    acc[2] = fmaf(v1, bflo(u1.y), acc[2]);
    acc[3] = fmaf(v1, bfhi(u1.y), acc[3]);
    acc[4] = fmaf(v1, bflo(u1.z), acc[4]);
    acc[5] = fmaf(v1, bfhi(u1.z), acc[5]);
    acc[6] = fmaf(v1, bflo(u1.w), acc[6]);
    acc[7] = fmaf(v1, bfhi(u1.w), acc[7]);
    acc[0] = fmaf(v2, bflo(u2.x), acc[0]);
    acc[1] = fmaf(v2, bfhi(u2.x), acc[1]);
    acc[2] = fmaf(v2, bflo(u2.y), acc[2]);
    acc[3] = fmaf(v2, bfhi(u2.y), acc[3]);
    acc[4] = fmaf(v2, bflo(u2.z), acc[4]);
    acc[5] = fmaf(v2, bfhi(u2.z), acc[5]);
    acc[6] = fmaf(v2, bflo(u2.w), acc[6]);
    acc[7] = fmaf(v2, bfhi(u2.w), acc[7]);
    acc[0] = fmaf(v3, bflo(u3.x), acc[0]);
    acc[1] = fmaf(v3, bfhi(u3.x), acc[1]);
    acc[2] = fmaf(v3, bflo(u3.y), acc[2]);
    acc[3] = fmaf(v3, bfhi(u3.y), acc[3]);
    acc[4] = fmaf(v3, bflo(u3.z), acc[4]);
    acc[5] = fmaf(v3, bfhi(u3.z), acc[5]);
    acc[6] = fmaf(v3, bflo(u3.w), acc[6]);
    acc[7] = fmaf(v3, bfhi(u3.w), acc[7]);
  }
  #pragma unroll
  for (int t = 0; t < 8; ++t) {
    acc[t] += __shfl_xor(acc[t], 16);
    acc[t] += __shfl_xor(acc[t], 32);
  }
  if (eg == 0) {
    size_t ro = ((size_t)(b * N_ + n)) * C_ + cl * 8;
    uint4 p;
    p.x = (u32)f2bf(acc[0]) | ((u32)f2bf(acc[1]) << 16);
    p.y = (u32)f2bf(acc[2]) | ((u32)f2bf(acc[3]) << 16);
    p.z = (u32)f2bf(acc[4]) | ((u32)f2bf(acc[5]) << 16);
    p.w = (u32)f2bf(acc[6]) | ((u32)f2bf(acc[7]) << 16);
    *reinterpret_cast<uint4*>(dst + ro) = p;
  }
}

// ---- fused GEMM: out = relu(bias + xb@W0' + g1@W1' + g2@W2' + g3@W3') ----
// block = 256 (4 waves); each wave: 32 rows (2 m-tiles) x 128 cols, K = 512.

__global__ __launch_bounds__(256) void gemm_kernel(const u16* __restrict__ xb,
                                                   const u16* __restrict__ g1,
                                                   const u16* __restrict__ g2,
                                                   const u16* __restrict__ g3,
                                                   const u16* __restrict__ wf,
                                                   const float* __restrict__ bias,
                                                   float* __restrict__ out) {
  int lane = threadIdx.x & 63;
  int w = threadIdx.x >> 6;
  int xcd = blockIdx.x & 7;
  int j = blockIdx.x >> 3;                 // 0..63
  int b = xcd * 2 + (j >> 5);
  int mb = b * N_ + (j & 31) * 128 + w * 32;
  int g  = lane >> 4;
  int rl = lane & 15;
  const u16* srcs[4] = {xb, g1, g2, g3};
  f32x4 acc0[8], acc1[8];
  #pragma unroll
  for (int t = 0; t < 8; ++t) {
    acc0[t] = (f32x4){0.f, 0.f, 0.f, 0.f};
    acc1[t] = (f32x4){0.f, 0.f, 0.f, 0.f};
  }
  size_t mrow = (size_t)(mb + rl) * C_;
  for (int ks = 0; ks < 16; ++ks) {
    const u16* ap = srcs[ks >> 2] + mrow + (ks & 3) * 32 + g * 8;
    s16x8 a0 = *reinterpret_cast<const s16x8*>(ap);
    s16x8 a1 = *reinterpret_cast<const s16x8*>(ap + 16 * C_);
    const s16x8* wp = reinterpret_cast<const s16x8*>(wf) + (ks * 8) * 64 + lane;
    #pragma unroll
    for (int ct = 0; ct < 8; ++ct) {
      s16x8 bfv = wp[ct * 64];
      acc0[ct] = __builtin_amdgcn_mfma_f32_16x16x32_bf16(a0, bfv, acc0[ct], 0, 0, 0);
      acc1[ct] = __builtin_amdgcn_mfma_f32_16x16x32_bf16(a1, bfv, acc1[ct], 0, 0, 0);
    }
  }
  #pragma unroll
  for (int ct = 0; ct < 8; ++ct) {
    int o = ct * 16 + rl;
    float bo = bias[o];
    #pragma unroll
    for (int r = 0; r < 4; ++r) {
      int m0 = mb + g * 4 + r;
      int m1 = mb + 16 + g * 4 + r;
      float v0 = acc0[ct][r] + bo;
      float v1 = acc1[ct][r] + bo;
      out[(size_t)m0 * C_ + o] = v0 > 0.f ? v0 : 0.f;
      out[(size_t)m1 * C_ + o] = v1 > 0.f ? v1 : 0.f;
    }
  }
}

// ---- launch --------------------------------------------------------------

extern "C" void kernel_launch(void* const* d_in, const int* in_sizes, int n_in,
                              void* d_out, int out_size, void* d_ws, size_t ws_size,
                              hipStream_t stream) {
  (void)in_sizes; (void)n_in; (void)out_size; (void)ws_size;
  const float* x    = (const float*)d_in[0];
  const float* vals = (const float*)d_in[1];
  const float* wts  = (const float*)d_in[2];
  const float* bias = (const float*)d_in[3];
  const int*   rows = (const int*)d_in[4];
  const int*   cols = (const int*)d_in[5];
  float* out = (float*)d_out;

  const size_t SB = (size_t)B_ * N_ * C_ * sizeof(u16);   // 16.78 MB
  char* ws = (char*)d_ws;
  u16* xb = (u16*)ws;
  u16* g1 = (u16*)(ws + SB);
  u16* g2 = (u16*)(ws + 2 * SB);
  u16* g3 = (u16*)(ws + 3 * SB);
  char* meta = ws + 4 * SB;
  int* hist = (int*)meta;                          // 16*16*4096*4 = 4 MB
  u32* ecv  = (u32*)(meta + 4194304);              // 16*ECAP*4   = 5.24 MB
  int* cnt  = (int*)(meta + 9437184);              // B*N*4       = 256 KB
  int* off  = (int*)(meta + 9699328);              // B*(N+1)*4   = 262208 B
  u16* wf   = (u16*)(meta + 9961536);              // 128 KB

  prep_kernel<<<4608, 256, 0, stream>>>(x, xb, wts, wf, rows, hist);
  rowscan_kernel<<<256, 256, 0, stream>>>(hist, cnt);
  scan_kernel<<<16, 256, 0, stream>>>(cnt, off);
  scatter2_kernel<<<256, 256, 0, stream>>>(rows, cols, vals, off, hist, cnt, ecv);
  // g1 = L x ; g2 = L g1 ; g3 = L g2
  spmm_kernel<<<(B_ * N_) / 4, 256, 0, stream>>>(xb, g1, ecv, off);
  spmm_kernel<<<(B_ * N_) / 4, 256, 0, stream>>>(g1, g2, ecv, off);
  spmm_kernel<<<(B_ * N_) / 4, 256, 0, stream>>>(g2, g3, ecv, off);
  // out = relu(bias + xb@(W0-W2) + g1@(W1-3W3) + g2@(2W2) + g3@(4W3))
  gemm_kernel<<<(B_ * N_) / 128, 256, 0, stream>>>(xb, g1, g2, g3, wf, bias, out);
}

// Round 6
// 119.153 us; speedup vs baseline: 2.5267x; 1.2136x over previous
//
#include <hip/hip_runtime.h>
#include <hip/hip_bf16.h>
#include <stdint.h>

#define B_ 16
#define N_ 4096
#define E_ 65536
#define C_ 128   // CIN == COUT
#define ECAP 81920  // padded edge capacity per batch (E + 3*N = 77824 max)

typedef unsigned short u16;
typedef unsigned int u32;
using f32x4 = __attribute__((ext_vector_type(4))) float;
using s16x8 = __attribute__((ext_vector_type(8))) short;

__device__ __forceinline__ u16 f2bf(float f) {
  u32 u = __builtin_bit_cast(u32, f);
  u = (u + 0x7FFFu + ((u >> 16) & 1u)) >> 16;
  return (u16)u;
}
__device__ __forceinline__ float bflo(u32 u) {   // low bf16 -> f32
  return __builtin_bit_cast(float, u << 16);
}
__device__ __forceinline__ float bfhi(u32 u) {   // high bf16 -> f32
  return __builtin_bit_cast(float, u & 0xFFFF0000u);
}

// ---- prep: fused xconv (blocks 0..4095) + wfrag (4096..4351) + hist (4352..4607)
// wfrag bakes the Chebyshev recombination:
//   out = x(W0-W2) + g1(W1-3W3) + g2(2W2) + g3(4W3),  g_k = L^k x

__global__ __launch_bounds__(256) void prep_kernel(const float* __restrict__ x,
                                                   u16* __restrict__ xb,
                                                   const float* __restrict__ w,
                                                   u16* __restrict__ wf,
                                                   const int* __restrict__ rows,
                                                   int* __restrict__ hist) {
  int blk = blockIdx.x;
  int t = threadIdx.x;
  if (blk < 4096) {
    // x -> bf16, XCD-pinned
    int xcd = blk & 7;
    int j   = blk >> 3;              // 0..511
    int b   = xcd * 2 + (j >> 8);
    size_t base = (size_t)b * N_ * C_ + ((j & 255) * 256 + t) * 8;
    const float4* xp = reinterpret_cast<const float4*>(x + base);
    float4 a0 = xp[0];
    float4 a1 = xp[1];
    uint4 p;
    p.x = (u32)f2bf(a0.x) | ((u32)f2bf(a0.y) << 16);
    p.y = (u32)f2bf(a0.z) | ((u32)f2bf(a0.w) << 16);
    p.z = (u32)f2bf(a1.x) | ((u32)f2bf(a1.y) << 16);
    p.w = (u32)f2bf(a1.z) | ((u32)f2bf(a1.w) << 16);
    *reinterpret_cast<uint4*>(xb + base) = p;
  } else if (blk < 4352) {
    // W fragment pack with recombined weights, MFMA B-operand order
    int tid = (blk - 4096) * 256 + t;   // 0..65535
    int j  = tid & 7;
    int l  = (tid >> 3) & 63;
    int ct = (tid >> 9) & 7;
    int ks = tid >> 12;
    int g  = l >> 4;
    int k  = ks * 32 + g * 8 + j;       // 0..511
    int kk = k >> 7;
    int i  = k & 127;
    int o  = ct * 16 + (l & 15);
    float a = w[(kk * C_ + i) * C_ + o];
    float r;
    if (kk == 0)      r = a - w[(2 * C_ + i) * C_ + o];
    else if (kk == 1) r = a - 3.f * w[(3 * C_ + i) * C_ + o];
    else if (kk == 2) r = 2.f * a;
    else              r = 4.f * a;
    wf[tid] = f2bf(r);
  } else {
    // per-(batch,chunk) LDS histogram of rows
    __shared__ int h[N_];
    int hblk = blk - 4352;              // 0..255
    int b = hblk >> 4;
    int c = hblk & 15;
    #pragma unroll
    for (int i = 0; i < 16; ++i) h[t + 256 * i] = 0;
    __syncthreads();
    int ebase = b * E_ + c * 4096;
    #pragma unroll
    for (int i = 0; i < 16; ++i) {
      int r = rows[ebase + t + 256 * i];
      atomicAdd(&h[r], 1);              // LDS atomic
    }
    __syncthreads();
    int4* hg = reinterpret_cast<int4*>(hist + (size_t)hblk * 4096);
    const int4* hl = reinterpret_cast<const int4*>(h);
    #pragma unroll
    for (int i = 0; i < 4; ++i) hg[t + 256 * i] = hl[t + 256 * i];
  }
}

// per-row exclusive scan over the 16 chunk counts (in-place), emit row totals
__global__ __launch_bounds__(256) void rowscan_kernel(int* __restrict__ hist,
                                                      int* __restrict__ cnt) {
  int rg = blockIdx.x * 256 + threadIdx.x;   // 0..65535 = b*4096+r
  int b = rg >> 12;
  int r = rg & 4095;
  int base = (b * 16) * 4096 + r;
  int h[16];
  #pragma unroll
  for (int c = 0; c < 16; ++c) h[c] = hist[base + c * 4096];
  int run = 0;
  #pragma unroll
  for (int c = 0; c < 16; ++c) {
    int v = h[c];
    hist[base + c * 4096] = run;
    run += v;
  }
  cnt[rg] = run;
}

// per-batch exclusive scan of PADDED row totals -> off (4-aligned row starts)
__global__ __launch_bounds__(256) void scan_kernel(const int* __restrict__ cnt,
                                                   int* __restrict__ off) {
  __shared__ int psum[256];
  int b = (blockIdx.x & 7) * 2 + (blockIdx.x >> 3);
  int t = threadIdx.x;
  int local[16];
  int s = 0;
  int base = b * N_ + t * 16;
  #pragma unroll
  for (int i = 0; i < 16; ++i) {
    local[i] = (cnt[base + i] + 3) & ~3;   // pad each row to multiple of 4
    s += local[i];
  }
  psum[t] = s;
  __syncthreads();
  if (t == 0) {
    int run = 0;
    for (int i = 0; i < 256; ++i) { int v = psum[i]; psum[i] = run; run += v; }
  }
  __syncthreads();
  int run = psum[t];
  int ob = b * (N_ + 1) + t * 16;
  #pragma unroll
  for (int i = 0; i < 16; ++i) { off[ob + i] = run; run += local[i]; }
  if (t == 255) off[b * (N_ + 1) + N_] = run;
}

// scatter edges row-sorted; rank via LDS atomics; payload col|bf16(val);
// chunk-0 blocks also zero-fill the pad slots of every row.
__global__ __launch_bounds__(256) void scatter2_kernel(const int* __restrict__ rows,
                                                       const int* __restrict__ cols,
                                                       const float* __restrict__ vals,
                                                       const int* __restrict__ off,
                                                       const int* __restrict__ hist,
                                                       const int* __restrict__ cnt,
                                                       u32* __restrict__ ecv) {
  __shared__ int base[N_];
  __shared__ int cur[N_];
  int xcd = blockIdx.x & 7;
  int j   = blockIdx.x >> 3;              // 0..31
  int b   = xcd * 2 + (j >> 4);
  int c   = j & 15;
  int t   = threadIdx.x;
  const int* hb = hist + (b * 16 + c) * 4096;
  const int* ob = off + b * (N_ + 1);
  #pragma unroll
  for (int i = 0; i < 16; ++i) {
    int idx = t + 256 * i;
    base[idx] = ob[idx] + hb[idx];
    cur[idx] = 0;
  }
  __syncthreads();
  int ebase = b * E_ + c * 4096;
  u32* ecvb = ecv + (size_t)b * ECAP;
  #pragma unroll
  for (int i = 0; i < 16; ++i) {
    int e = ebase + t + 256 * i;
    int r = rows[e];
    int rank = atomicAdd(&cur[r], 1);     // LDS atomic
    u32 pv = (u32)cols[e] | ((u32)f2bf(vals[e]) << 16);
    ecvb[base[r] + rank] = pv;
  }
  if (c == 0) {
    // zero the pad tail of each row (disjoint from all real-edge slots)
    #pragma unroll
    for (int i = 0; i < 16; ++i) {
      int r = t + 256 * i;
      int real = cnt[b * N_ + r];
      int pbase = ob[r] + real;
      int pad = (-real) & 3;
      for (int k = 0; k < pad; ++k) ecvb[pbase + k] = 0;
    }
  }
}

// ---- SpMM (bf16, pure L): dst[row] = sum val_e * src[col_e]
// wave = 2 rows x 2 group-slots x 16 channel-lanes; slot loads uint4 = 4 edges.
// slots {0,1} -> row n0, slots {2,3} -> row n1 (consecutive rows).

__global__ __launch_bounds__(256) void spmm_kernel(const u16* __restrict__ src,
                                                   u16* __restrict__ dst,
                                                   const u32* __restrict__ ecv,
                                                   const int* __restrict__ off) {
  int lane = threadIdx.x & 63;
  int wv   = threadIdx.x >> 6;
  int xcd  = blockIdx.x & 7;
  int j    = blockIdx.x >> 3;          // 0..1023
  int b    = xcd * 2 + (j >> 9);
  int rp   = ((j & 511) << 2) | wv;    // row pair 0..2047
  int eg   = lane >> 4;                // slot 0..3
  int cl   = lane & 15;                // channel group (8 bf16 = 16B)
  int n    = rp * 2 + (eg >> 1);       // this lane's row
  int sub  = eg & 1;                   // sub-slot within row
  int s4 = off[b * (N_ + 1) + n] >> 2;
  int e4 = off[b * (N_ + 1) + n + 1] >> 2;
  const uint4* ecv4 = reinterpret_cast<const uint4*>(ecv + (size_t)b * ECAP);
  const u16* srcb = src + (size_t)b * N_ * C_;
  float acc[8];
  #pragma unroll
  for (int t = 0; t < 8; ++t) acc[t] = 0.f;
  for (int gp = s4 + sub; gp < e4; gp += 2) {
    uint4 cv = ecv4[gp];
    u32 e0 = cv.x, e1 = cv.y, e2 = cv.z, e3 = cv.w;
    uint4 u0 = *reinterpret_cast<const uint4*>(srcb + (size_t)(e0 & 0xFFFFu) * C_ + cl * 8);
    uint4 u1 = *reinterpret_cast<const uint4*>(srcb + (size_t)(e1 & 0xFFFFu) * C_ + cl * 8);
    uint4 u2 = *reinterpret_cast<const uint4*>(srcb + (size_t)(e2 & 0xFFFFu) * C_ + cl * 8);
    uint4 u3 = *reinterpret_cast<const uint4*>(srcb + (size_t)(e3 & 0xFFFFu) * C_ + cl * 8);
    float v0 = bfhi(e0), v1 = bfhi(e1), v2 = bfhi(e2), v3 = bfhi(e3);
    acc[0] = fmaf(v0, bflo(u0.x), acc[0]);
    acc[1] = fmaf(v0, bfhi(u0.x), acc[1]);
    acc[2] = fmaf(v0, bflo(u0.y), acc[2]);
    acc[3] = fmaf(v0, bfhi(u0.y), acc[3]);
    acc[4] = fmaf(v0, bflo(u0.z), acc[4]);
    acc[5] = fmaf(v0, bfhi(u0.z), acc[5]);
    acc[6] = fmaf(v0, bflo(u0.w), acc[6]);
    acc[7] = fmaf(v0, bfhi(u0.w), acc[7]);
    acc[0] = fmaf(v1, bflo(u1.x), acc[0]);
    acc[1] = fmaf(v1, bfhi(u1.x), acc[1]);
    acc[2] = fmaf(v1, bflo(u1.y), acc[2]);
    acc[3] = fmaf(v1, bfhi(u1.y), acc[3]);
    acc[4] = fmaf(v1, bflo(u1.z), acc[4]);
    acc[5] = fmaf(v1, bfhi(u1.z), acc[5]);
    acc[6] = fmaf(v1, bflo(u1.w), acc[6]);
    acc[7] = fmaf(v1, bfhi(u1.w), acc[7]);
    acc[0] = fmaf(v2, bflo(u2.x), acc[0]);
    acc[1] = fmaf(v2, bfhi(u2.x), acc[1]);
    acc[2] = fmaf(v2, bflo(u2.y), acc[2]);
    acc[3] = fmaf(v2, bfhi(u2.y), acc[3]);
    acc[4] = fmaf(v2, bflo(u2.z), acc[4]);
    acc[5] = fmaf(v2, bfhi(u2.z), acc[5]);
    acc[6] = fmaf(v2, bflo(u2.w), acc[6]);
    acc[7] = fmaf(v2, bfhi(u2.w), acc[7]);
    acc[0] = fmaf(v3, bflo(u3.x), acc[0]);
    acc[1] = fmaf(v3, bfhi(u3.x), acc[1]);
    acc[2] = fmaf(v3, bflo(u3.y), acc[2]);
    acc[3] = fmaf(v3, bfhi(u3.y), acc[3]);
    acc[4] = fmaf(v3, bflo(u3.z), acc[4]);
    acc[5] = fmaf(v3, bfhi(u3.z), acc[5]);
    acc[6] = fmaf(v3, bflo(u3.w), acc[6]);
    acc[7] = fmaf(v3, bfhi(u3.w), acc[7]);
  }
  // sum sub-slot pairs: lanes l and l^16 hold the same row
  #pragma unroll
  for (int t = 0; t < 8; ++t) acc[t] += __shfl_xor(acc[t], 16);
  if (sub == 0) {   // slots 0 and 2 write rows n0, n1
    size_t ro = ((size_t)(b * N_ + n)) * C_ + cl * 8;
    uint4 p;
    p.x = (u32)f2bf(acc[0]) | ((u32)f2bf(acc[1]) << 16);
    p.y = (u32)f2bf(acc[2]) | ((u32)f2bf(acc[3]) << 16);
    p.z = (u32)f2bf(acc[4]) | ((u32)f2bf(acc[5]) << 16);
    p.w = (u32)f2bf(acc[6]) | ((u32)f2bf(acc[7]) << 16);
    *reinterpret_cast<uint4*>(dst + ro) = p;
  }
}

// ---- fused GEMM: out = relu(bias + xb@W0' + g1@W1' + g2@W2' + g3@W3') ----
// 512-thread block (8 waves); wf staged in 128 KiB LDS; wave: 32 rows x 128 cols.
// grid 256 = 1 block/CU; B-operands via conflict-free ds_read_b128.

__global__ __launch_bounds__(512) void gemm_kernel(const u16* __restrict__ xb,
                                                   const u16* __restrict__ g1,
                                                   const u16* __restrict__ g2,
                                                   const u16* __restrict__ g3,
                                                   const u16* __restrict__ wf,
                                                   const float* __restrict__ bias,
                                                   float* __restrict__ out) {
  __shared__ u16 wls[65536];            // 128 KiB: full recombined W (512x128)
  int tid = threadIdx.x;
  // stage wf -> LDS (8192 x 16B chunks over 512 threads)
  #pragma unroll
  for (int i = 0; i < 16; ++i) {
    int chunk = i * 512 + tid;
    reinterpret_cast<uint4*>(wls)[chunk] = reinterpret_cast<const uint4*>(wf)[chunk];
  }
  __syncthreads();
  int lane = tid & 63;
  int w = tid >> 6;                        // wave 0..7
  int xcd = blockIdx.x & 7;
  int j = blockIdx.x >> 3;                 // 0..31
  int b = xcd * 2 + (j >> 4);
  int mb = b * N_ + (j & 15) * 256 + w * 32;
  int g  = lane >> 4;
  int rl = lane & 15;
  const u16* srcs[4] = {xb, g1, g2, g3};
  f32x4 acc0[8], acc1[8];
  #pragma unroll
  for (int t = 0; t < 8; ++t) {
    acc0[t] = (f32x4){0.f, 0.f, 0.f, 0.f};
    acc1[t] = (f32x4){0.f, 0.f, 0.f, 0.f};
  }
  size_t mrow = (size_t)(mb + rl) * C_;
  for (int ks = 0; ks < 16; ++ks) {
    const u16* ap = srcs[ks >> 2] + mrow + (ks & 3) * 32 + g * 8;
    s16x8 a0 = *reinterpret_cast<const s16x8*>(ap);
    s16x8 a1 = *reinterpret_cast<const s16x8*>(ap + 16 * C_);
    const u16* wp = wls + (ks * 8) * 512 + lane * 8;
    #pragma unroll
    for (int ct = 0; ct < 8; ++ct) {
      s16x8 bfv = *reinterpret_cast<const s16x8*>(wp + ct * 512);
      acc0[ct] = __builtin_amdgcn_mfma_f32_16x16x32_bf16(a0, bfv, acc0[ct], 0, 0, 0);
      acc1[ct] = __builtin_amdgcn_mfma_f32_16x16x32_bf16(a1, bfv, acc1[ct], 0, 0, 0);
    }
  }
  #pragma unroll
  for (int ct = 0; ct < 8; ++ct) {
    int o = ct * 16 + rl;
    float bo = bias[o];
    #pragma unroll
    for (int r = 0; r < 4; ++r) {
      int m0 = mb + g * 4 + r;
      int m1 = mb + 16 + g * 4 + r;
      float v0 = acc0[ct][r] + bo;
      float v1 = acc1[ct][r] + bo;
      out[(size_t)m0 * C_ + o] = v0 > 0.f ? v0 : 0.f;
      out[(size_t)m1 * C_ + o] = v1 > 0.f ? v1 : 0.f;
    }
  }
}

// ---- launch --------------------------------------------------------------

extern "C" void kernel_launch(void* const* d_in, const int* in_sizes, int n_in,
                              void* d_out, int out_size, void* d_ws, size_t ws_size,
                              hipStream_t stream) {
  (void)in_sizes; (void)n_in; (void)out_size; (void)ws_size;
  const float* x    = (const float*)d_in[0];
  const float* vals = (const float*)d_in[1];
  const float* wts  = (const float*)d_in[2];
  const float* bias = (const float*)d_in[3];
  const int*   rows = (const int*)d_in[4];
  const int*   cols = (const int*)d_in[5];
  float* out = (float*)d_out;

  const size_t SB = (size_t)B_ * N_ * C_ * sizeof(u16);   // 16.78 MB
  char* ws = (char*)d_ws;
  u16* xb = (u16*)ws;
  u16* g1 = (u16*)(ws + SB);
  u16* g2 = (u16*)(ws + 2 * SB);
  u16* g3 = (u16*)(ws + 3 * SB);
  char* meta = ws + 4 * SB;
  int* hist = (int*)meta;                          // 16*16*4096*4 = 4 MB
  u32* ecv  = (u32*)(meta + 4194304);              // 16*ECAP*4   = 5.24 MB
  int* cnt  = (int*)(meta + 9437184);              // B*N*4       = 256 KB
  int* off  = (int*)(meta + 9699328);              // B*(N+1)*4   = 262208 B
  u16* wf   = (u16*)(meta + 9961536);              // 128 KB

  prep_kernel<<<4608, 256, 0, stream>>>(x, xb, wts, wf, rows, hist);
  rowscan_kernel<<<256, 256, 0, stream>>>(hist, cnt);
  scan_kernel<<<16, 256, 0, stream>>>(cnt, off);
  scatter2_kernel<<<256, 256, 0, stream>>>(rows, cols, vals, off, hist, cnt, ecv);
  // g1 = L x ; g2 = L g1 ; g3 = L g2
  spmm_kernel<<<8192, 256, 0, stream>>>(xb, g1, ecv, off);
  spmm_kernel<<<8192, 256, 0, stream>>>(g1, g2, ecv, off);
  spmm_kernel<<<8192, 256, 0, stream>>>(g2, g3, ecv, off);
  // out = relu(bias + xb@(W0-W2) + g1@(W1-3W3) + g2@(2W2) + g3@(4W3))
  gemm_kernel<<<256, 512, 0, stream>>>(xb, g1, g2, g3, wf, bias, out);
}